// Round 1
// baseline (122.857 us; speedup 1.0000x reference)
//
#include <hip/hip_runtime.h>
#include <hip/hip_bf16.h>

#define IH   48
#define IW   48
#define CH   64
#define KS   7
#define LN_EPS 1e-5f
#define QSCALE 0.35355339059327373f

#define TS   8                   /* output tile side (8x8 = 64 px) */
#define HS   14                  /* halo side: 8 + 2*3 */
#define HP   196                 /* halo pixels 14*14 */
#define KVS  128                 /* kv LDS row: k[64]+v[64] bf16 (256 B) */
#define AOS  72                  /* attn-out LDS row stride bf16 (144 B) */

typedef __bf16 bf16_t;
typedef bf16_t bf16x8 __attribute__((ext_vector_type(8)));
typedef float  f32x4  __attribute__((ext_vector_type(4)));
typedef float  f32x2  __attribute__((ext_vector_type(2)));

__device__ __forceinline__ float bflo(unsigned u) { union { unsigned i; float f; } v; v.i = u << 16; return v.f; }
__device__ __forceinline__ float bfhi(unsigned u) { union { unsigned i; float f; } v; v.i = u & 0xffff0000u; return v.f; }
__device__ __forceinline__ f32x2 unp2(unsigned u) { f32x2 r; r.x = bflo(u); r.y = bfhi(u); return r; }

// unaligned (4-B) float4 load — compiler emits global_load_dwordx4 / dwords
__device__ __forceinline__ float4 ldf4u(const float* p) {
    float4 r; __builtin_memcpy(&r, p, 16); return r;
}

__device__ __forceinline__ bf16x8 pack_bf16x8(float4 lo, float4 hi) {
    bf16x8 r;
    r[0] = (bf16_t)lo.x; r[1] = (bf16_t)lo.y; r[2] = (bf16_t)lo.z; r[3] = (bf16_t)lo.w;
    r[4] = (bf16_t)hi.x; r[5] = (bf16_t)hi.y; r[6] = (bf16_t)hi.z; r[7] = (bf16_t)hi.w;
    return r;
}

// One block per 8x8 output tile of one image.
// Phase A: QKV projection (MFMA) -> Q(64px) + K/V(196px halo) into LDS.
// Phase B: paired-pixel neighborhood attention, K/V from LDS.
// Phase C: proj + LN (MFMA), 4 waves x 16-pixel m-tiles.
__global__ __launch_bounds__(256, 2) void fused_na_kernel(
        const float* __restrict__ x,
        const float* __restrict__ w,      // qkv_w [192][64]
        const float* __restrict__ b,      // qkv_b [192]
        const float* __restrict__ rpb,
        const float* __restrict__ pw,     // proj_w [64][64]
        const float* __restrict__ pb,
        const float* __restrict__ g,
        const float* __restrict__ beta,
        float* __restrict__ out) {
    __shared__ __align__(16) __hip_bfloat16 kv[HP * KVS];    // 50,176 B
    __shared__ __align__(16) __hip_bfloat16 qao[64 * AOS];   //  9,216 B (q stride 64, then ao stride 72)

    const int blk  = blockIdx.x;         // 0..575
    const int n    = blk & 15;           // image
    const int tile = blk >> 4;           // 0..35
    const int i0   = (tile / 6) * TS;
    const int j0   = (tile % 6) * TS;
    int h0 = i0 - 3; h0 = h0 < 0 ? 0 : (h0 > IH - HS ? IH - HS : h0);
    int w0 = j0 - 3; w0 = w0 < 0 ? 0 : (w0 > IW - HS ? IW - HS : w0);
    const int tid = threadIdx.x;
    const size_t img = (size_t)n * (IH * IW);

    // ---------------- phase A: QKV -> LDS --------------------------------
    {
        const int wv = tid >> 6;         // 0..3
        const int l  = tid & 63;
        const int m  = l & 15;
        const int kg = l >> 4;

        // ---- Q: interior 64 px (each wave one 16-px m-tile) ----
        {
            const int ch_base = m * 4;
            const float4 bias4 = *(const float4*)(b + ch_base);
            bf16x8 wb0[4], wb1[4];
            #pragma unroll
            for (int t = 0; t < 4; ++t) {
                const float* wr_ = w + (size_t)(ch_base + t) * CH + kg * 8;
                wb0[t] = pack_bf16x8(*(const float4*)(wr_),      *(const float4*)(wr_ + 4));
                wb1[t] = pack_bf16x8(*(const float4*)(wr_ + 32), *(const float4*)(wr_ + 36));
            }
            const int px = wv * 16 + m;
            const int hr = i0 + (px >> 3);
            const int wc = j0 + (px & 7);
            const float* xr = x + (img + hr * IW + wc) * CH + kg * 8;
            const bf16x8 a0 = pack_bf16x8(*(const float4*)(xr),      *(const float4*)(xr + 4));
            const bf16x8 a1 = pack_bf16x8(*(const float4*)(xr + 32), *(const float4*)(xr + 36));
            float val[4][4];
            #pragma unroll
            for (int t = 0; t < 4; ++t) {
                f32x4 acc = {0.f, 0.f, 0.f, 0.f};
                acc = __builtin_amdgcn_mfma_f32_16x16x32_bf16(a0, wb0[t], acc, 0, 0, 0);
                acc = __builtin_amdgcn_mfma_f32_16x16x32_bf16(a1, wb1[t], acc, 0, 0, 0);
                const float bias = (t == 0) ? bias4.x : (t == 1) ? bias4.y : (t == 2) ? bias4.z : bias4.w;
                #pragma unroll
                for (int rr = 0; rr < 4; ++rr) val[t][rr] = (acc[rr] + bias) * QSCALE;
            }
            #pragma unroll
            for (int rr = 0; rr < 4; ++rr) {
                const int pix = wv * 16 + kg * 4 + rr;
                union { ushort4 u; __hip_bfloat16 hh[4]; } pk;
                #pragma unroll
                for (int t = 0; t < 4; ++t) pk.hh[t] = __float2bfloat16(val[t][rr]);
                *reinterpret_cast<ushort4*>(qao + pix * 64 + ch_base) = pk.u;
            }
        }

        // ---- K,V: 196 halo px (13 m-tiles round-robined over waves) ----
        for (int grp = 1; grp < 3; ++grp) {
            const int ch_base = grp * 64 + m * 4;
            const float4 bias4 = *(const float4*)(b + ch_base);
            bf16x8 wb0[4], wb1[4];
            #pragma unroll
            for (int t = 0; t < 4; ++t) {
                const float* wr_ = w + (size_t)(ch_base + t) * CH + kg * 8;
                wb0[t] = pack_bf16x8(*(const float4*)(wr_),      *(const float4*)(wr_ + 4));
                wb1[t] = pack_bf16x8(*(const float4*)(wr_ + 32), *(const float4*)(wr_ + 36));
            }
            for (int mt = wv; mt < 13; mt += 4) {
                int hp = mt * 16 + m; if (hp > HP - 1) hp = HP - 1;   // clamped A-row only feeds skipped D-rows
                const int hr = h0 + hp / HS;
                const int wc = w0 + hp % HS;
                const float* xr = x + (img + hr * IW + wc) * CH + kg * 8;
                const bf16x8 a0 = pack_bf16x8(*(const float4*)(xr),      *(const float4*)(xr + 4));
                const bf16x8 a1 = pack_bf16x8(*(const float4*)(xr + 32), *(const float4*)(xr + 36));
                float val[4][4];
                #pragma unroll
                for (int t = 0; t < 4; ++t) {
                    f32x4 acc = {0.f, 0.f, 0.f, 0.f};
                    acc = __builtin_amdgcn_mfma_f32_16x16x32_bf16(a0, wb0[t], acc, 0, 0, 0);
                    acc = __builtin_amdgcn_mfma_f32_16x16x32_bf16(a1, wb1[t], acc, 0, 0, 0);
                    const float bias = (t == 0) ? bias4.x : (t == 1) ? bias4.y : (t == 2) ? bias4.z : bias4.w;
                    #pragma unroll
                    for (int rr = 0; rr < 4; ++rr) val[t][rr] = acc[rr] + bias;
                }
                #pragma unroll
                for (int rr = 0; rr < 4; ++rr) {
                    const int pix = mt * 16 + kg * 4 + rr;
                    if (pix < HP) {
                        union { ushort4 u; __hip_bfloat16 hh[4]; } pk;
                        #pragma unroll
                        for (int t = 0; t < 4; ++t) pk.hh[t] = __float2bfloat16(val[t][rr]);
                        *reinterpret_cast<ushort4*>(kv + pix * KVS + (grp - 1) * 64 + m * 4) = pk.u;
                    }
                }
            }
        }
    }
    __syncthreads();

    // ---------------- phase B: paired-pixel attention (K/V in LDS) -------
    {
        const int h  = tid & 7;
        const int pr = tid >> 3;             // 0..31
        const int pi = pr >> 3;              // 0..3  (== tid>>6, wave-uniform)
        const int pj = pr & 7;
        const int i  = i0 + pi * 2;
        const int j  = j0 + pj;
        const int pl0 = pi * 16 + pj;        // local pixel (i ,j)
        const int pl1 = pl0 + 8;             // local pixel (i+1,j)

        f32x2 q0[4], q1[4];
        {
            const uint4 u = *reinterpret_cast<const uint4*>(qao + pl0 * 64 + h * 8);
            q0[0] = unp2(u.x); q0[1] = unp2(u.y); q0[2] = unp2(u.z); q0[3] = unp2(u.w);
            const uint4 v = *reinterpret_cast<const uint4*>(qao + pl1 * 64 + h * 8);
            q1[0] = unp2(v.x); q1[1] = unp2(v.y); q1[2] = unp2(v.z); q1[3] = unp2(v.w);
        }
        __syncthreads();                     // qao region is reused for attn-out below

        int si0 = i - 3;     si0 = si0 < 0 ? 0 : (si0 > IH - KS ? IH - KS : si0);
        int si1 = i - 2;     si1 = si1 < 0 ? 0 : (si1 > IH - KS ? IH - KS : si1);
        int sj  = j - 3;     sj  = sj  < 0 ? 0 : (sj  > IW - KS ? IW - KS : sj);
        const int off    = si1 - si0;        // 0 or 1, wave-uniform
        const int rbase0 = si0 - i + 6;      // 1..6
        const float* rpc = rpb + h * (2*KS-1) * (2*KS-1) + (sj - j + (KS - 1));
        const int c0 = sj - w0;              // halo col of first key

        float lr0 = 0.f, lr1 = 0.f;
        f32x2 a0[4], a1[4];
        #pragma unroll
        for (int d = 0; d < 4; ++d) { a0[d] = (f32x2){0.f,0.f}; a1[d] = (f32x2){0.f,0.f}; }

        for (int p = 0; p < 8; ++p) {        // union of both pixels' window rows
            if (p == 7 && off == 0) break;   // uniform: 8th row unused
            const bool d0 = (p < 7);
            const bool d1 = (p > 0) || (off == 0);
            const __hip_bfloat16* row = kv + ((si0 + p - h0) * HS + c0) * KVS + h * 8;

            uint4 kb[KS], vb[KS];
            #pragma unroll
            for (int qq = 0; qq < KS; ++qq) {
                kb[qq] = *reinterpret_cast<const uint4*>(row + qq * KVS);
                vb[qq] = *reinterpret_cast<const uint4*>(row + qq * KVS + 64);
            }
            float4 r0a = {0,0,0,0}, r0b = {0,0,0,0}, r1a = {0,0,0,0}, r1b = {0,0,0,0};
            if (d0) {
                const float* rr = rpc + (rbase0 + p) * (2*KS-1);
                r0a = ldf4u(rr); r0b = ldf4u(rr + 3);
            }
            if (d1) {
                const float* rr = rpc + (rbase0 - 1 + p) * (2*KS-1);
                r1a = ldf4u(rr); r1b = ldf4u(rr + 3);
            }

            float s0[KS], s1[KS];
            #pragma unroll
            for (int qq = 0; qq < KS; ++qq) {
                const f32x2 k0 = unp2(kb[qq].x), k1 = unp2(kb[qq].y);
                const f32x2 k2 = unp2(kb[qq].z), k3 = unp2(kb[qq].w);
                f32x2 t0 = q0[0]*k0 + q0[1]*k1 + q0[2]*k2 + q0[3]*k3;
                f32x2 t1 = q1[0]*k0 + q1[1]*k1 + q1[2]*k2 + q1[3]*k3;
                s0[qq] = t0.x + t0.y;
                s1[qq] = t1.x + t1.y;
            }
            float e0[KS], e1[KS];
            #pragma unroll
            for (int qq = 0; qq < KS; ++qq) { e0[qq] = 0.f; e1[qq] = 0.f; }
            if (d0) {
                e0[0] = __expf(s0[0] + r0a.x); e0[1] = __expf(s0[1] + r0a.y);
                e0[2] = __expf(s0[2] + r0a.z); e0[3] = __expf(s0[3] + r0a.w);
                e0[4] = __expf(s0[4] + r0b.y); e0[5] = __expf(s0[5] + r0b.z);
                e0[6] = __expf(s0[6] + r0b.w);
            }
            if (d1) {
                e1[0] = __expf(s1[0] + r1a.x); e1[1] = __expf(s1[1] + r1a.y);
                e1[2] = __expf(s1[2] + r1a.z); e1[3] = __expf(s1[3] + r1a.w);
                e1[4] = __expf(s1[4] + r1b.y); e1[5] = __expf(s1[5] + r1b.z);
                e1[6] = __expf(s1[6] + r1b.w);
            }
            #pragma unroll
            for (int qq = 0; qq < KS; ++qq) {
                const f32x2 v0 = unp2(vb[qq].x), v1 = unp2(vb[qq].y);
                const f32x2 v2 = unp2(vb[qq].z), v3 = unp2(vb[qq].w);
                lr0 += e0[qq];
                a0[0] += e0[qq] * v0; a0[1] += e0[qq] * v1;
                a0[2] += e0[qq] * v2; a0[3] += e0[qq] * v3;
                lr1 += e1[qq];
                a1[0] += e1[qq] * v0; a1[1] += e1[qq] * v1;
                a1[2] += e1[qq] * v2; a1[3] += e1[qq] * v3;
            }
        }
        const float inv0 = 1.f / lr0;
        const float inv1 = 1.f / lr1;
        union { uint4 u; __hip_bfloat16 hh[8]; } pk;
        #pragma unroll
        for (int d = 0; d < 4; ++d) {
            pk.hh[2*d]   = __float2bfloat16(a0[d].x * inv0);
            pk.hh[2*d+1] = __float2bfloat16(a0[d].y * inv0);
        }
        *reinterpret_cast<uint4*>(qao + pl0 * AOS + h * 8) = pk.u;
        #pragma unroll
        for (int d = 0; d < 4; ++d) {
            pk.hh[2*d]   = __float2bfloat16(a1[d].x * inv1);
            pk.hh[2*d+1] = __float2bfloat16(a1[d].y * inv1);
        }
        *reinterpret_cast<uint4*>(qao + pl1 * AOS + h * 8) = pk.u;
    }
    __syncthreads();

    // ---------------- phase C: proj + LN (4 waves, 4 m-tiles) ------------
    {
        const int wv = tid >> 6;             // 0..3
        const int l  = tid & 63;
        const int m  = l & 15;
        const int kg = l >> 4;

        const __hip_bfloat16* ar = qao + (wv * 16 + m) * AOS + kg * 8;
        const bf16x8 a0 = *reinterpret_cast<const bf16x8*>(ar);
        const bf16x8 a1 = *reinterpret_cast<const bf16x8*>(ar + 32);

        const int ch_base = m * 4;
        const float4 bias4 = *(const float4*)(pb + ch_base);

        float val[4][4];                                   // [t][r], ch = m*4+t
        #pragma unroll
        for (int t = 0; t < 4; ++t) {
            const float* wr_ = pw + (size_t)(ch_base + t) * CH + kg * 8;  // permuted B row
            const bf16x8 b0 = pack_bf16x8(*(const float4*)(wr_),      *(const float4*)(wr_ + 4));
            const bf16x8 b1 = pack_bf16x8(*(const float4*)(wr_ + 32), *(const float4*)(wr_ + 36));
            f32x4 acc = {0.f, 0.f, 0.f, 0.f};
            acc = __builtin_amdgcn_mfma_f32_16x16x32_bf16(a0, b0, acc, 0, 0, 0);
            acc = __builtin_amdgcn_mfma_f32_16x16x32_bf16(a1, b1, acc, 0, 0, 0);
            const float bias = (t == 0) ? bias4.x : (t == 1) ? bias4.y : (t == 2) ? bias4.z : bias4.w;
            #pragma unroll
            for (int r = 0; r < 4; ++r) val[t][r] = acc[r] + bias;
        }

        float sm[4];
        #pragma unroll
        for (int r = 0; r < 4; ++r) sm[r] = val[0][r] + val[1][r] + val[2][r] + val[3][r];
        #pragma unroll
        for (int mask = 1; mask <= 8; mask <<= 1) {
            #pragma unroll
            for (int r = 0; r < 4; ++r) sm[r] += __shfl_xor(sm[r], mask, 64);
        }
        float mu[4];
        #pragma unroll
        for (int r = 0; r < 4; ++r) mu[r] = sm[r] * (1.f / 64.f);

        float qs[4];
        #pragma unroll
        for (int r = 0; r < 4; ++r) {
            float a = val[0][r] - mu[r], bq = val[1][r] - mu[r];
            float c = val[2][r] - mu[r], d = val[3][r] - mu[r];
            qs[r] = a * a + bq * bq + c * c + d * d;
        }
        #pragma unroll
        for (int mask = 1; mask <= 8; mask <<= 1) {
            #pragma unroll
            for (int r = 0; r < 4; ++r) qs[r] += __shfl_xor(qs[r], mask, 64);
        }
        float rs[4];
        #pragma unroll
        for (int r = 0; r < 4; ++r) rs[r] = rsqrtf(qs[r] * (1.f / 64.f) + LN_EPS);

        const float4 g4  = *(const float4*)(g + ch_base);
        const float4 be4 = *(const float4*)(beta + ch_base);
        #pragma unroll
        for (int r = 0; r < 4; ++r) {
            const int pl = wv * 16 + kg * 4 + r;          // local pixel 0..63
            const int gi = i0 + (pl >> 3), gj = j0 + (pl & 7);
            float4 o;
            o.x = (val[0][r] - mu[r]) * rs[r] * g4.x + be4.x;
            o.y = (val[1][r] - mu[r]) * rs[r] * g4.y + be4.y;
            o.z = (val[2][r] - mu[r]) * rs[r] * g4.z + be4.z;
            o.w = (val[3][r] - mu[r]) * rs[r] * g4.w + be4.w;
            *reinterpret_cast<float4*>(out + (img + gi * IW + gj) * CH + ch_base) = o;
        }
    }
}

extern "C" void kernel_launch(void* const* d_in, const int* in_sizes, int n_in,
                              void* d_out, int out_size, void* d_ws, size_t ws_size,
                              hipStream_t stream) {
    const float* x      = (const float*)d_in[0];
    const float* qkv_w  = (const float*)d_in[1];
    const float* qkv_b  = (const float*)d_in[2];
    const float* proj_w = (const float*)d_in[3];
    const float* proj_b = (const float*)d_in[4];
    const float* rpb    = (const float*)d_in[5];
    const float* ln_g   = (const float*)d_in[6];
    const float* ln_b   = (const float*)d_in[7];
    float* out = (float*)d_out;

    // fully fused: no workspace, no intermediate qkv round-trip
    fused_na_kernel<<<576, 256, 0, stream>>>(x, qkv_w, qkv_b, rpb,
                                             proj_w, proj_b, ln_g, ln_b, out);
}

// Round 2
// 118.948 us; speedup vs baseline: 1.0329x; 1.0329x over previous
//
#include <hip/hip_runtime.h>
#include <hip/hip_bf16.h>

#define IH   48
#define IW   48
#define CH   64
#define KS   7
#define LN_EPS 1e-5f
#define QSCALE 0.35355339059327373f
#define L2E    1.4426950408889634f

#define TS   8                   /* output tile side (8x8 = 64 px) */
#define HS   14                  /* halo side: 8 + 2*3 */
#define HP   196                 /* halo pixels 14*14 */
#define KVS  128                 /* kv LDS row: k[64]+v[64] bf16 (256 B) */
#define AOS  72                  /* attn-out LDS row stride bf16 (144 B) */

typedef __bf16 bf16_t;
typedef bf16_t bf16x8 __attribute__((ext_vector_type(8)));
typedef float  f32x4  __attribute__((ext_vector_type(4)));
typedef float  f32x2  __attribute__((ext_vector_type(2)));

__device__ __forceinline__ float bflo(unsigned u) { union { unsigned i; float f; } v; v.i = u << 16; return v.f; }
__device__ __forceinline__ float bfhi(unsigned u) { union { unsigned i; float f; } v; v.i = u & 0xffff0000u; return v.f; }
__device__ __forceinline__ f32x2 unp2(unsigned u) { f32x2 r; r.x = bflo(u); r.y = bfhi(u); return r; }

__device__ __forceinline__ float4 ldf4u(const float* p) {
    float4 r; __builtin_memcpy(&r, p, 16); return r;
}

__device__ __forceinline__ bf16x8 pack_bf16x8(float4 lo, float4 hi) {
    bf16x8 r;
    r[0] = (bf16_t)lo.x; r[1] = (bf16_t)lo.y; r[2] = (bf16_t)lo.z; r[3] = (bf16_t)lo.w;
    r[4] = (bf16_t)hi.x; r[5] = (bf16_t)hi.y; r[6] = (bf16_t)hi.z; r[7] = (bf16_t)hi.w;
    return r;
}

// One block per 8x8 output tile. 512 threads (8 waves), 2 blocks/CU (59 KB LDS)
// -> 16 waves/CU = 4/SIMD (2x round-1 occupancy).
// Phase A: QKV projection (MFMA). 30 units = 4 Q m-tiles + 13 KV m-tiles x 2
//          groups; each wave holds ONE group's weight set in registers.
// Phase B: one thread per (pixel, head) — uniform 7x7 window, no divergence,
//          K/V from LDS, exp2-folded softmax taps.
// Phase C: proj + LN (MFMA), waves 0-3.
__global__ __launch_bounds__(512, 4) void fused_na_kernel(
        const float* __restrict__ x,
        const float* __restrict__ w,      // qkv_w [192][64]
        const float* __restrict__ b,      // qkv_b [192]
        const float* __restrict__ rpb,
        const float* __restrict__ pw,     // proj_w [64][64]
        const float* __restrict__ pb,
        const float* __restrict__ g,
        const float* __restrict__ beta,
        float* __restrict__ out) {
    __shared__ __align__(16) __hip_bfloat16 kv[HP * KVS];    // 50,176 B
    __shared__ __align__(16) __hip_bfloat16 qao[64 * AOS];   //  9,216 B

    const int blk  = blockIdx.x;         // 0..575
    const int n    = blk & 15;           // image
    const int tile = blk >> 4;           // 0..35
    const int i0   = (tile / 6) * TS;
    const int j0   = (tile % 6) * TS;
    int h0 = i0 - 3; h0 = h0 < 0 ? 0 : (h0 > IH - HS ? IH - HS : h0);
    int w0 = j0 - 3; w0 = w0 < 0 ? 0 : (w0 > IW - HS ? IW - HS : w0);
    const int tid = threadIdx.x;
    const size_t img = (size_t)n * (IH * IW);

    // ---------------- phase A: QKV -> LDS --------------------------------
    {
        const int wv = tid >> 6;         // 0..7
        const int l  = tid & 63;
        const int m  = l & 15;
        const int kg = l >> 4;

        // ---- Q: interior 64 px, waves 0-3 (one 16-px m-tile each) ----
        if (wv < 4) {
            const int ch_base = m * 4;
            const float4 bias4 = *(const float4*)(b + ch_base);
            bf16x8 wb0[4], wb1[4];
            #pragma unroll
            for (int t = 0; t < 4; ++t) {
                const float* wr_ = w + (size_t)(ch_base + t) * CH + kg * 8;
                wb0[t] = pack_bf16x8(*(const float4*)(wr_),      *(const float4*)(wr_ + 4));
                wb1[t] = pack_bf16x8(*(const float4*)(wr_ + 32), *(const float4*)(wr_ + 36));
            }
            const int px = wv * 16 + m;
            const int hr = i0 + (px >> 3);
            const int wc = j0 + (px & 7);
            const float* xr = x + (img + hr * IW + wc) * CH + kg * 8;
            const bf16x8 a0 = pack_bf16x8(*(const float4*)(xr),      *(const float4*)(xr + 4));
            const bf16x8 a1 = pack_bf16x8(*(const float4*)(xr + 32), *(const float4*)(xr + 36));
            float val[4][4];
            #pragma unroll
            for (int t = 0; t < 4; ++t) {
                f32x4 acc = {0.f, 0.f, 0.f, 0.f};
                acc = __builtin_amdgcn_mfma_f32_16x16x32_bf16(a0, wb0[t], acc, 0, 0, 0);
                acc = __builtin_amdgcn_mfma_f32_16x16x32_bf16(a1, wb1[t], acc, 0, 0, 0);
                const float bias = (t == 0) ? bias4.x : (t == 1) ? bias4.y : (t == 2) ? bias4.z : bias4.w;
                #pragma unroll
                for (int rr = 0; rr < 4; ++rr) val[t][rr] = (acc[rr] + bias) * (QSCALE * L2E);
            }
            #pragma unroll
            for (int rr = 0; rr < 4; ++rr) {
                const int pix = wv * 16 + kg * 4 + rr;
                union { ushort4 u; __hip_bfloat16 hh[4]; } pk;
                #pragma unroll
                for (int t = 0; t < 4; ++t) pk.hh[t] = __float2bfloat16(val[t][rr]);
                *reinterpret_cast<ushort4*>(qao + pix * 64 + ch_base) = pk.u;
            }
        }

        // ---- K,V: 196 halo px. grp fixed per wave-half; 13 m-tiles / 4 ----
        {
            const int grp = 1 + (wv >> 2);               // waves 0-3: K, 4-7: V
            const int ch_base = grp * 64 + m * 4;
            const float4 bias4 = *(const float4*)(b + ch_base);
            bf16x8 wb0[4], wb1[4];
            #pragma unroll
            for (int t = 0; t < 4; ++t) {
                const float* wr_ = w + (size_t)(ch_base + t) * CH + kg * 8;
                wb0[t] = pack_bf16x8(*(const float4*)(wr_),      *(const float4*)(wr_ + 4));
                wb1[t] = pack_bf16x8(*(const float4*)(wr_ + 32), *(const float4*)(wr_ + 36));
            }
            for (int mt = wv & 3; mt < 13; mt += 4) {
                int hp = mt * 16 + m; if (hp > HP - 1) hp = HP - 1;   // clamped A-row feeds only skipped D-rows
                const int hr = h0 + hp / HS;
                const int wc = w0 + hp % HS;
                const float* xr = x + (img + hr * IW + wc) * CH + kg * 8;
                const bf16x8 a0 = pack_bf16x8(*(const float4*)(xr),      *(const float4*)(xr + 4));
                const bf16x8 a1 = pack_bf16x8(*(const float4*)(xr + 32), *(const float4*)(xr + 36));
                float val[4][4];
                #pragma unroll
                for (int t = 0; t < 4; ++t) {
                    f32x4 acc = {0.f, 0.f, 0.f, 0.f};
                    acc = __builtin_amdgcn_mfma_f32_16x16x32_bf16(a0, wb0[t], acc, 0, 0, 0);
                    acc = __builtin_amdgcn_mfma_f32_16x16x32_bf16(a1, wb1[t], acc, 0, 0, 0);
                    const float bias = (t == 0) ? bias4.x : (t == 1) ? bias4.y : (t == 2) ? bias4.z : bias4.w;
                    #pragma unroll
                    for (int rr = 0; rr < 4; ++rr) val[t][rr] = acc[rr] + bias;
                }
                #pragma unroll
                for (int rr = 0; rr < 4; ++rr) {
                    const int pix = mt * 16 + kg * 4 + rr;
                    if (pix < HP) {
                        union { ushort4 u; __hip_bfloat16 hh[4]; } pk;
                        #pragma unroll
                        for (int t = 0; t < 4; ++t) pk.hh[t] = __float2bfloat16(val[t][rr]);
                        *reinterpret_cast<ushort4*>(kv + pix * KVS + (grp - 1) * 64 + m * 4) = pk.u;
                    }
                }
            }
        }
    }
    __syncthreads();

    // ---------------- phase B: per-(pixel,head) attention, K/V in LDS ----
    {
        const int h  = tid & 7;
        const int px = tid >> 3;             // 0..63
        const int i  = i0 + (px >> 3);
        const int j  = j0 + (px & 7);

        f32x2 q0[4];
        {
            const uint4 u = *reinterpret_cast<const uint4*>(qao + px * 64 + h * 8);
            q0[0] = unp2(u.x); q0[1] = unp2(u.y); q0[2] = unp2(u.z); q0[3] = unp2(u.w);
        }
        __syncthreads();                     // qao region reused for attn-out

        int si = i - 3;  si = si < 0 ? 0 : (si > IH - KS ? IH - KS : si);
        int sj = j - 3;  sj = sj < 0 ? 0 : (sj > IW - KS ? IW - KS : sj);
        const float* rpc = rpb + h * (2*KS-1) * (2*KS-1)
                               + (si - i + (KS-1)) * (2*KS-1) + (sj - j + (KS-1));
        const __hip_bfloat16* kbase = kv + ((si - h0) * HS + (sj - w0)) * KVS + h * 8;

        float lr = 0.f;
        f32x2 a[4];
        #pragma unroll
        for (int d = 0; d < 4; ++d) a[d] = (f32x2){0.f, 0.f};

        for (int p = 0; p < KS; ++p) {       // uniform 7 rows, no divergence
            const __hip_bfloat16* row = kbase + p * (HS * KVS);
            uint4 kb[KS], vb[KS];
            #pragma unroll
            for (int qq = 0; qq < KS; ++qq) {
                kb[qq] = *reinterpret_cast<const uint4*>(row + qq * KVS);
                vb[qq] = *reinterpret_cast<const uint4*>(row + qq * KVS + 64);
            }
            const float* rr = rpc + p * (2*KS-1);
            const float4 ba = ldf4u(rr);
            const float4 bb = ldf4u(rr + 3);

            float s[KS];
            #pragma unroll
            for (int qq = 0; qq < KS; ++qq) {
                const f32x2 k0 = unp2(kb[qq].x), k1 = unp2(kb[qq].y);
                const f32x2 k2 = unp2(kb[qq].z), k3 = unp2(kb[qq].w);
                f32x2 t = q0[0]*k0 + q0[1]*k1 + q0[2]*k2 + q0[3]*k3;
                s[qq] = t.x + t.y;
            }
            float e[KS];
            e[0] = __builtin_amdgcn_exp2f(fmaf(ba.x, L2E, s[0]));
            e[1] = __builtin_amdgcn_exp2f(fmaf(ba.y, L2E, s[1]));
            e[2] = __builtin_amdgcn_exp2f(fmaf(ba.z, L2E, s[2]));
            e[3] = __builtin_amdgcn_exp2f(fmaf(ba.w, L2E, s[3]));
            e[4] = __builtin_amdgcn_exp2f(fmaf(bb.y, L2E, s[4]));
            e[5] = __builtin_amdgcn_exp2f(fmaf(bb.z, L2E, s[5]));
            e[6] = __builtin_amdgcn_exp2f(fmaf(bb.w, L2E, s[6]));

            #pragma unroll
            for (int qq = 0; qq < KS; ++qq) {
                const f32x2 v0 = unp2(vb[qq].x), v1 = unp2(vb[qq].y);
                const f32x2 v2 = unp2(vb[qq].z), v3 = unp2(vb[qq].w);
                lr += e[qq];
                a[0] += e[qq] * v0; a[1] += e[qq] * v1;
                a[2] += e[qq] * v2; a[3] += e[qq] * v3;
            }
        }
        const float inv = 1.f / lr;
        union { uint4 u; __hip_bfloat16 hh[8]; } pk;
        #pragma unroll
        for (int d = 0; d < 4; ++d) {
            pk.hh[2*d]   = __float2bfloat16(a[d].x * inv);
            pk.hh[2*d+1] = __float2bfloat16(a[d].y * inv);
        }
        *reinterpret_cast<uint4*>(qao + px * AOS + h * 8) = pk.u;
    }
    __syncthreads();

    // ---------------- phase C: proj + LN (waves 0-3, 4 m-tiles) ----------
    if ((tid >> 6) < 4) {
        const int wv = tid >> 6;             // 0..3
        const int l  = tid & 63;
        const int m  = l & 15;
        const int kg = l >> 4;

        const __hip_bfloat16* ar = qao + (wv * 16 + m) * AOS + kg * 8;
        const bf16x8 a0 = *reinterpret_cast<const bf16x8*>(ar);
        const bf16x8 a1 = *reinterpret_cast<const bf16x8*>(ar + 32);

        const int ch_base = m * 4;
        const float4 bias4 = *(const float4*)(pb + ch_base);

        float val[4][4];                                   // [t][r], ch = m*4+t
        #pragma unroll
        for (int t = 0; t < 4; ++t) {
            const float* wr_ = pw + (size_t)(ch_base + t) * CH + kg * 8;  // permuted B row
            const bf16x8 b0 = pack_bf16x8(*(const float4*)(wr_),      *(const float4*)(wr_ + 4));
            const bf16x8 b1 = pack_bf16x8(*(const float4*)(wr_ + 32), *(const float4*)(wr_ + 36));
            f32x4 acc = {0.f, 0.f, 0.f, 0.f};
            acc = __builtin_amdgcn_mfma_f32_16x16x32_bf16(a0, b0, acc, 0, 0, 0);
            acc = __builtin_amdgcn_mfma_f32_16x16x32_bf16(a1, b1, acc, 0, 0, 0);
            const float bias = (t == 0) ? bias4.x : (t == 1) ? bias4.y : (t == 2) ? bias4.z : bias4.w;
            #pragma unroll
            for (int r = 0; r < 4; ++r) val[t][r] = acc[r] + bias;
        }

        float sm[4];
        #pragma unroll
        for (int r = 0; r < 4; ++r) sm[r] = val[0][r] + val[1][r] + val[2][r] + val[3][r];
        #pragma unroll
        for (int mask = 1; mask <= 8; mask <<= 1) {
            #pragma unroll
            for (int r = 0; r < 4; ++r) sm[r] += __shfl_xor(sm[r], mask, 64);
        }
        float mu[4];
        #pragma unroll
        for (int r = 0; r < 4; ++r) mu[r] = sm[r] * (1.f / 64.f);

        float qs[4];
        #pragma unroll
        for (int r = 0; r < 4; ++r) {
            float aa = val[0][r] - mu[r], bq = val[1][r] - mu[r];
            float c  = val[2][r] - mu[r], d  = val[3][r] - mu[r];
            qs[r] = aa * aa + bq * bq + c * c + d * d;
        }
        #pragma unroll
        for (int mask = 1; mask <= 8; mask <<= 1) {
            #pragma unroll
            for (int r = 0; r < 4; ++r) qs[r] += __shfl_xor(qs[r], mask, 64);
        }
        float rs[4];
        #pragma unroll
        for (int r = 0; r < 4; ++r) rs[r] = rsqrtf(qs[r] * (1.f / 64.f) + LN_EPS);

        const float4 g4  = *(const float4*)(g + ch_base);
        const float4 be4 = *(const float4*)(beta + ch_base);
        #pragma unroll
        for (int r = 0; r < 4; ++r) {
            const int pl = wv * 16 + kg * 4 + r;          // local pixel 0..63
            const int gi = i0 + (pl >> 3), gj = j0 + (pl & 7);
            float4 o;
            o.x = (val[0][r] - mu[r]) * rs[r] * g4.x + be4.x;
            o.y = (val[1][r] - mu[r]) * rs[r] * g4.y + be4.y;
            o.z = (val[2][r] - mu[r]) * rs[r] * g4.z + be4.z;
            o.w = (val[3][r] - mu[r]) * rs[r] * g4.w + be4.w;
            *reinterpret_cast<float4*>(out + (img + gi * IW + gj) * CH + ch_base) = o;
        }
    }
}

extern "C" void kernel_launch(void* const* d_in, const int* in_sizes, int n_in,
                              void* d_out, int out_size, void* d_ws, size_t ws_size,
                              hipStream_t stream) {
    const float* x      = (const float*)d_in[0];
    const float* qkv_w  = (const float*)d_in[1];
    const float* qkv_b  = (const float*)d_in[2];
    const float* proj_w = (const float*)d_in[3];
    const float* proj_b = (const float*)d_in[4];
    const float* rpb    = (const float*)d_in[5];
    const float* ln_g   = (const float*)d_in[6];
    const float* ln_b   = (const float*)d_in[7];
    float* out = (float*)d_out;

    fused_na_kernel<<<576, 512, 0, stream>>>(x, qkv_w, qkv_b, rpb,
                                             proj_w, proj_b, ln_g, ln_b, out);
}